// Round 2
// baseline (353.070 us; speedup 1.0000x reference)
//
#include <hip/hip_runtime.h>

typedef int v4i  __attribute__((ext_vector_type(4)));
typedef int v16i __attribute__((ext_vector_type(16)));

#define DIN 1024
#define QMAXF 127.0f

// One wave (64 lanes) per row of 1024 floats. Rows [0,M) are x; rows [M, M+DOUT) are weight.
// Each lane handles 4 float4s (lane + 64*i), covering all 1024 floats of the row.
__global__ __launch_bounds__(256) void quant_rows(
    const float* __restrict__ x, const float* __restrict__ w,
    char* __restrict__ xq, char* __restrict__ wq,
    float* __restrict__ xscale, float* __restrict__ wscale, int M)
{
    int wave = threadIdx.x >> 6;
    int lane = threadIdx.x & 63;
    int r = blockIdx.x * 4 + wave;

    const float* src;
    char* dst;
    float* sout;
    if (r < M) {
        src  = x  + (size_t)r * DIN;
        dst  = xq + (size_t)r * DIN;
        sout = xscale + r;
    } else {
        int rw = r - M;
        src  = w  + (size_t)rw * DIN;
        dst  = wq + (size_t)rw * DIN;
        sout = wscale + rw;
    }

    float4 v[4];
    #pragma unroll
    for (int i = 0; i < 4; i++)
        v[i] = ((const float4*)src)[lane + 64 * i];

    float a = 0.0f;
    #pragma unroll
    for (int i = 0; i < 4; i++) {
        a = fmaxf(a, fmaxf(fmaxf(fabsf(v[i].x), fabsf(v[i].y)),
                           fmaxf(fabsf(v[i].z), fabsf(v[i].w))));
    }
    #pragma unroll
    for (int off = 32; off; off >>= 1)
        a = fmaxf(a, __shfl_xor(a, off));
    a = fmaxf(a, 1e-8f);

    float inv = QMAXF / a;
    #pragma unroll
    for (int i = 0; i < 4; i++) {
        int q0 = max(-128, min(127, __float2int_rn(v[i].x * inv)));
        int q1 = max(-128, min(127, __float2int_rn(v[i].y * inv)));
        int q2 = max(-128, min(127, __float2int_rn(v[i].z * inv)));
        int q3 = max(-128, min(127, __float2int_rn(v[i].w * inv)));
        unsigned pk = (unsigned)(q0 & 255) | ((unsigned)(q1 & 255) << 8) |
                      ((unsigned)(q2 & 255) << 16) | ((unsigned)(q3 & 255) << 24);
        ((unsigned*)dst)[lane + 64 * i] = pk;
    }
    if (lane == 0) *sout = a / QMAXF;
}

// C = Aq(M x K) * Bq(N x K)^T, int8 -> int32 exact, then dequant + bias.
// Block tile 128x128, 4 waves (2x2), each wave 64x64 via 2x2 mfma_i32_32x32x32_i8.
// No LDS: per-lane MFMA fragments are contiguous 16B global loads; L1/L2/L3 serve reuse.
__global__ __launch_bounds__(256, 4) void gemm_i8(
    const char* __restrict__ Aq, const char* __restrict__ Bq,
    const float* __restrict__ xscale, const float* __restrict__ wscale,
    const float* __restrict__ bias, float* __restrict__ out,
    int n_tiles, int N)
{
    int bx = blockIdx.x;
    int mt = bx / n_tiles;
    int nt = bx - mt * n_tiles;
    int m0 = mt * 128;
    int n0 = nt * 128;

    int wave = threadIdx.x >> 6;
    int lane = threadIdx.x & 63;
    int wm = (wave & 1) * 64;   // wave offset in M within the block tile
    int wn = (wave >> 1) * 64;  // wave offset in N
    int frow = lane & 31;       // fragment row (m for A, n for B)
    int kh = (lane >> 5) * 16;  // K half selected by upper/lower 32 lanes

    const char* ap = Aq + (size_t)(m0 + wm + frow) * DIN + kh;
    const char* bp = Bq + (size_t)(n0 + wn + frow) * DIN + kh;

    v16i acc00 = {}; v16i acc01 = {}; v16i acc10 = {}; v16i acc11 = {};

    #pragma unroll 4
    for (int k = 0; k < DIN; k += 32) {
        v4i a0 = *(const v4i*)(ap);
        v4i a1 = *(const v4i*)(ap + 32 * DIN);
        v4i b0 = *(const v4i*)(bp);
        v4i b1 = *(const v4i*)(bp + 32 * DIN);
        ap += 32; bp += 32;
        acc00 = __builtin_amdgcn_mfma_i32_32x32x32_i8(a0, b0, acc00, 0, 0, 0);
        acc01 = __builtin_amdgcn_mfma_i32_32x32x32_i8(a0, b1, acc01, 0, 0, 0);
        acc10 = __builtin_amdgcn_mfma_i32_32x32x32_i8(a1, b0, acc10, 0, 0, 0);
        acc11 = __builtin_amdgcn_mfma_i32_32x32x32_i8(a1, b1, acc11, 0, 0, 0);
    }

    // C/D layout (verified, dtype-independent): col = lane&31, row = (reg&3) + 8*(reg>>2) + 4*(lane>>5)
    int n_lane = lane & 31;
    int rquad = 4 * (lane >> 5);
    v16i accs[2][2] = {{acc00, acc01}, {acc10, acc11}};
    #pragma unroll
    for (int i = 0; i < 2; i++) {
        int mbase = m0 + wm + i * 32;
        #pragma unroll
        for (int j = 0; j < 2; j++) {
            int n = n0 + wn + j * 32 + n_lane;
            float wsn = wscale[n];
            float bn = bias[n];
            v16i A = accs[i][j];
            #pragma unroll
            for (int r = 0; r < 16; r++) {
                int m = mbase + (r & 3) + 8 * (r >> 2) + rquad;
                out[(size_t)m * N + n] = (float)A[r] * xscale[m] * wsn + bn;
            }
        }
    }
}

extern "C" void kernel_launch(void* const* d_in, const int* in_sizes, int n_in,
                              void* d_out, int out_size, void* d_ws, size_t ws_size,
                              hipStream_t stream)
{
    const float* x    = (const float*)d_in[0];
    const float* w    = (const float*)d_in[1];
    const float* bias = (const float*)d_in[2];
    float* out = (float*)d_out;

    int DOUT = in_sizes[2];        // 1024
    int M = in_sizes[0] / DIN;     // 32768

    char* ws  = (char*)d_ws;
    char* xq  = ws;
    char* wq  = ws + (size_t)M * DIN;
    float* xs = (float*)(wq + (size_t)DOUT * DIN);
    float* wsc = xs + M;

    int rows = M + DOUT;           // 33792, divisible by 4
    quant_rows<<<rows / 4, 256, 0, stream>>>(x, w, xq, wq, xs, wsc, M);

    int n_tiles = DOUT / 128;      // 8
    int grid = (M / 128) * n_tiles; // 2048
    gemm_i8<<<grid, 256, 0, stream>>>(xq, wq, xs, wsc, bias, out, n_tiles, DOUT);
}

// Round 3
// 298.239 us; speedup vs baseline: 1.1839x; 1.1839x over previous
//
#include <hip/hip_runtime.h>
#include <stdint.h>

typedef int v4i  __attribute__((ext_vector_type(4)));
typedef int v16i __attribute__((ext_vector_type(16)));

#define DIN 1024
#define QMAXF 127.0f

// One wave (64 lanes) per row of 1024 floats. Rows [0,M) are x; rows [M, M+DOUT) are weight.
__global__ __launch_bounds__(256) void quant_rows(
    const float* __restrict__ x, const float* __restrict__ w,
    char* __restrict__ xq, char* __restrict__ wq,
    float* __restrict__ xscale, float* __restrict__ wscale, int M)
{
    int wave = threadIdx.x >> 6;
    int lane = threadIdx.x & 63;
    int r = blockIdx.x * 4 + wave;

    const float* src;
    char* dst;
    float* sout;
    if (r < M) {
        src  = x  + (size_t)r * DIN;
        dst  = xq + (size_t)r * DIN;
        sout = xscale + r;
    } else {
        int rw = r - M;
        src  = w  + (size_t)rw * DIN;
        dst  = wq + (size_t)rw * DIN;
        sout = wscale + rw;
    }

    float4 v[4];
    #pragma unroll
    for (int i = 0; i < 4; i++)
        v[i] = ((const float4*)src)[lane + 64 * i];

    float a = 0.0f;
    #pragma unroll
    for (int i = 0; i < 4; i++) {
        a = fmaxf(a, fmaxf(fmaxf(fabsf(v[i].x), fabsf(v[i].y)),
                           fmaxf(fabsf(v[i].z), fabsf(v[i].w))));
    }
    #pragma unroll
    for (int off = 32; off; off >>= 1)
        a = fmaxf(a, __shfl_xor(a, off));
    a = fmaxf(a, 1e-8f);

    float inv = QMAXF / a;
    #pragma unroll
    for (int i = 0; i < 4; i++) {
        int q0 = max(-128, min(127, __float2int_rn(v[i].x * inv)));
        int q1 = max(-128, min(127, __float2int_rn(v[i].y * inv)));
        int q2 = max(-128, min(127, __float2int_rn(v[i].z * inv)));
        int q3 = max(-128, min(127, __float2int_rn(v[i].w * inv)));
        unsigned pk = (unsigned)(q0 & 255) | ((unsigned)(q1 & 255) << 8) |
                      ((unsigned)(q2 & 255) << 16) | ((unsigned)(q3 & 255) << 24);
        ((unsigned*)dst)[lane + 64 * i] = pk;
    }
    if (lane == 0) *sout = a / QMAXF;
}

// Block = 64 token rows x full N=1024. 1024 threads = 16 waves, each wave a 64x64
// out tile (2x2 of mfma_i32_32x32x32_i8). x_q tile (64 KB) staged to LDS via
// global_load_lds(16B) with XOR chunk swizzle (applied on the GLOBAL read side,
// since the LDS dest is strictly base+lane*16): LDS row r chunk c holds global
// chunk (c ^ (r&7)), which spreads ds_read_b128 across banks at the 8-lane/bank
// data floor. B (wq, 1 MB total) is read direct from global and stays L2-hot.
__global__ __launch_bounds__(1024) void gemm_i8_lds(
    const char* __restrict__ Aq, const char* __restrict__ Bq,
    const float* __restrict__ xscale, const float* __restrict__ wscale,
    const float* __restrict__ bias, float* __restrict__ out, int N)
{
    __shared__ char As[64 * 1024];

    int m0 = blockIdx.x * 64;
    int w = threadIdx.x >> 6;
    int lane = threadIdx.x & 63;

    // ---- stage 64 rows of Aq into LDS (4 rows per wave, 1 KB per call) ----
    #pragma unroll
    for (int i = 0; i < 4; i++) {
        int r = w * 4 + i;
        int gchunk = lane ^ (r & 7);                       // swizzle on global side
        const char* gsrc = Aq + (size_t)(m0 + r) * DIN + gchunk * 16;
        char* ldst = As + r * 1024;                        // wave-uniform base
        __builtin_amdgcn_global_load_lds(
            (const __attribute__((address_space(1))) void*)gsrc,
            (__attribute__((address_space(3))) void*)ldst,
            16, 0, 0);
    }
    __syncthreads();

    // ---- K loop ----
    int frow = lane & 31;
    int sel  = lane >> 5;          // selects K half: kh = sel*16
    int wn   = w * 64;
    int xork = frow & 7;           // same key for row frow and frow+32 (32%8==0)

    const char* bp = Bq + (size_t)(wn + frow) * DIN + sel * 16;
    const char* As0 = As + frow * 1024;
    const char* As1 = As + (frow + 32) * 1024;

    v16i acc00 = {}; v16i acc01 = {}; v16i acc10 = {}; v16i acc11 = {};

    #pragma unroll 4
    for (int ks = 0; ks < 32; ks++) {
        int k = ks * 32;
        int coff = (((k >> 4) + sel) ^ xork) << 4;         // swizzled chunk byte offset
        v4i a0 = *(const v4i*)(As0 + coff);
        v4i a1 = *(const v4i*)(As1 + coff);
        v4i b0 = *(const v4i*)(bp + k);
        v4i b1 = *(const v4i*)(bp + k + (size_t)32 * DIN);
        acc00 = __builtin_amdgcn_mfma_i32_32x32x32_i8(a0, b0, acc00, 0, 0, 0);
        acc01 = __builtin_amdgcn_mfma_i32_32x32x32_i8(a0, b1, acc01, 0, 0, 0);
        acc10 = __builtin_amdgcn_mfma_i32_32x32x32_i8(a1, b0, acc10, 0, 0, 0);
        acc11 = __builtin_amdgcn_mfma_i32_32x32x32_i8(a1, b1, acc11, 0, 0, 0);
    }

    // ---- epilogue: C/D layout col=lane&31, row=(reg&3)+8*(reg>>2)+4*sel ----
    int n_lane = lane & 31;
    int rquad = 4 * sel;
    v16i accs[2][2] = {{acc00, acc01}, {acc10, acc11}};
    #pragma unroll
    for (int i = 0; i < 2; i++) {
        int mbase = m0 + i * 32;
        #pragma unroll
        for (int j = 0; j < 2; j++) {
            int n = wn + j * 32 + n_lane;
            float wsn = wscale[n];
            float bn = bias[n];
            v16i A = accs[i][j];
            #pragma unroll
            for (int r = 0; r < 16; r++) {
                int m = mbase + (r & 3) + 8 * (r >> 2) + rquad;
                __builtin_nontemporal_store((float)A[r] * xscale[m] * wsn + bn,
                                            &out[(size_t)m * N + n]);
            }
        }
    }
}

extern "C" void kernel_launch(void* const* d_in, const int* in_sizes, int n_in,
                              void* d_out, int out_size, void* d_ws, size_t ws_size,
                              hipStream_t stream)
{
    const float* x    = (const float*)d_in[0];
    const float* w    = (const float*)d_in[1];
    const float* bias = (const float*)d_in[2];
    float* out = (float*)d_out;

    int DOUT = in_sizes[2];        // 1024
    int M = in_sizes[0] / DIN;     // 32768

    char* ws  = (char*)d_ws;
    char* xq  = ws;
    char* wq  = ws + (size_t)M * DIN;
    float* xs = (float*)(wq + (size_t)DOUT * DIN);
    float* wsc = xs + M;

    int rows = M + DOUT;           // 33792, divisible by 4
    quant_rows<<<rows / 4, 256, 0, stream>>>(x, w, xq, wq, xs, wsc, M);

    gemm_i8_lds<<<M / 64, 1024, 0, stream>>>(xq, wq, xs, wsc, bias, out, DOUT);
}

// Round 4
// 294.108 us; speedup vs baseline: 1.2005x; 1.0140x over previous
//
#include <hip/hip_runtime.h>
#include <stdint.h>

typedef int v4i  __attribute__((ext_vector_type(4)));
typedef int v16i __attribute__((ext_vector_type(16)));

#define DIN 1024
#define QMAXF 127.0f

// Weight-only quant: one wave per row of 1024 floats (DOUT=1024 rows).
__global__ __launch_bounds__(256) void quant_w(
    const float* __restrict__ w, char* __restrict__ wq,
    float* __restrict__ wscale)
{
    int wave = threadIdx.x >> 6;
    int lane = threadIdx.x & 63;
    int r = blockIdx.x * 4 + wave;

    const float* src = w + (size_t)r * DIN;
    char* dst = wq + (size_t)r * DIN;

    float4 v[4];
    #pragma unroll
    for (int i = 0; i < 4; i++)
        v[i] = ((const float4*)src)[lane + 64 * i];

    float a = 0.0f;
    #pragma unroll
    for (int i = 0; i < 4; i++)
        a = fmaxf(a, fmaxf(fmaxf(fabsf(v[i].x), fabsf(v[i].y)),
                           fmaxf(fabsf(v[i].z), fabsf(v[i].w))));
    #pragma unroll
    for (int off = 32; off; off >>= 1)
        a = fmaxf(a, __shfl_xor(a, off));
    a = fmaxf(a, 1e-8f);

    float inv = QMAXF / a;
    #pragma unroll
    for (int i = 0; i < 4; i++) {
        int q0 = max(-128, min(127, __float2int_rn(v[i].x * inv)));
        int q1 = max(-128, min(127, __float2int_rn(v[i].y * inv)));
        int q2 = max(-128, min(127, __float2int_rn(v[i].z * inv)));
        int q3 = max(-128, min(127, __float2int_rn(v[i].w * inv)));
        unsigned pk = (unsigned)(q0 & 255) | ((unsigned)(q1 & 255) << 8) |
                      ((unsigned)(q2 & 255) << 16) | ((unsigned)(q3 & 255) << 24);
        ((unsigned*)dst)[lane + 64 * i] = pk;
    }
    if (lane == 0) wscale[r] = a / QMAXF;
}

// Fused per-token quant + int8 GEMM. Block = 64 token rows x full N=1024,
// 1024 threads = 16 waves. Quant phase: wave w quantizes rows 4w..4w+3 of x
// (fp32 read once from HBM), lane holds 16 contiguous floats -> 16 int8 bytes
// -> one ds_write_b128 at XOR-swizzled chunk (LDS row r chunk c holds data
// chunk c^(r&7)); row scale kept in LDS. K-loop: A from LDS, B (wq, L2-hot)
// from global with explicit next-iter register double-buffer.
__global__ __launch_bounds__(1024) void gemm_i8_fused(
    const float* __restrict__ x, const char* __restrict__ Bq,
    const float* __restrict__ wscale, const float* __restrict__ bias,
    float* __restrict__ out, int N)
{
    __shared__ char As[64 * 1024];
    __shared__ float xs_lds[64];

    int m0 = blockIdx.x * 64;
    int w = threadIdx.x >> 6;
    int lane = threadIdx.x & 63;

    // ---- fused quant phase: 4 rows per wave ----
    for (int i = 0; i < 4; i++) {
        int r = w * 4 + i;
        const float* src = x + (size_t)(m0 + r) * DIN;
        float4 v[4];
        #pragma unroll
        for (int j = 0; j < 4; j++)
            v[j] = ((const float4*)src)[lane * 4 + j];   // floats [16*lane,16*lane+16)

        float a = 0.0f;
        #pragma unroll
        for (int j = 0; j < 4; j++)
            a = fmaxf(a, fmaxf(fmaxf(fabsf(v[j].x), fabsf(v[j].y)),
                               fmaxf(fabsf(v[j].z), fabsf(v[j].w))));
        #pragma unroll
        for (int off = 32; off; off >>= 1)
            a = fmaxf(a, __shfl_xor(a, off));
        a = fmaxf(a, 1e-8f);

        float inv = QMAXF / a;
        int pk[4];
        #pragma unroll
        for (int j = 0; j < 4; j++) {
            int q0 = max(-128, min(127, __float2int_rn(v[j].x * inv)));
            int q1 = max(-128, min(127, __float2int_rn(v[j].y * inv)));
            int q2 = max(-128, min(127, __float2int_rn(v[j].z * inv)));
            int q3 = max(-128, min(127, __float2int_rn(v[j].w * inv)));
            pk[j] = (int)((unsigned)(q0 & 255) | ((unsigned)(q1 & 255) << 8) |
                          ((unsigned)(q2 & 255) << 16) | ((unsigned)(q3 & 255) << 24));
        }
        v4i pkv = { pk[0], pk[1], pk[2], pk[3] };
        *(v4i*)(As + r * 1024 + ((lane ^ (r & 7)) * 16)) = pkv;
        if (lane == 0) xs_lds[r] = a / QMAXF;
    }
    __syncthreads();

    // ---- K loop ----
    int frow = lane & 31;
    int sel  = lane >> 5;          // K half: kh = sel*16
    int wn   = w * 64;
    int xork = frow & 7;

    const char* bp = Bq + (size_t)(wn + frow) * DIN + sel * 16;
    const char* As0 = As + frow * 1024;
    const char* As1 = As + (frow + 32) * 1024;

    v16i acc00 = {}; v16i acc01 = {}; v16i acc10 = {}; v16i acc11 = {};

    v4i b0c = *(const v4i*)(bp);
    v4i b1c = *(const v4i*)(bp + (size_t)32 * DIN);

    #pragma unroll 4
    for (int ks = 0; ks < 32; ks++) {
        int k = ks * 32;
        v4i b0n, b1n;
        if (ks < 31) {
            b0n = *(const v4i*)(bp + k + 32);
            b1n = *(const v4i*)(bp + k + 32 + (size_t)32 * DIN);
        }
        int coff = (((k >> 4) + sel) ^ xork) << 4;
        v4i a0 = *(const v4i*)(As0 + coff);
        v4i a1 = *(const v4i*)(As1 + coff);
        acc00 = __builtin_amdgcn_mfma_i32_32x32x32_i8(a0, b0c, acc00, 0, 0, 0);
        acc01 = __builtin_amdgcn_mfma_i32_32x32x32_i8(a0, b1c, acc01, 0, 0, 0);
        acc10 = __builtin_amdgcn_mfma_i32_32x32x32_i8(a1, b0c, acc10, 0, 0, 0);
        acc11 = __builtin_amdgcn_mfma_i32_32x32x32_i8(a1, b1c, acc11, 0, 0, 0);
        b0c = b0n; b1c = b1n;
    }

    // ---- epilogue: C/D layout col=lane&31, row=(reg&3)+8*(reg>>2)+4*sel ----
    int n_lane = lane & 31;
    int rquad = 4 * sel;
    v16i accs[2][2] = {{acc00, acc01}, {acc10, acc11}};
    #pragma unroll
    for (int i = 0; i < 2; i++) {
        int mloc = i * 32;
        #pragma unroll
        for (int j = 0; j < 2; j++) {
            int n = wn + j * 32 + n_lane;
            float wsn = wscale[n];
            float bn = bias[n];
            v16i A = accs[i][j];
            #pragma unroll
            for (int r = 0; r < 16; r++) {
                int ml = mloc + (r & 3) + 8 * (r >> 2) + rquad;
                __builtin_nontemporal_store(
                    (float)A[r] * xs_lds[ml] * wsn + bn,
                    &out[(size_t)(m0 + ml) * N + n]);
            }
        }
    }
}

extern "C" void kernel_launch(void* const* d_in, const int* in_sizes, int n_in,
                              void* d_out, int out_size, void* d_ws, size_t ws_size,
                              hipStream_t stream)
{
    const float* x    = (const float*)d_in[0];
    const float* w    = (const float*)d_in[1];
    const float* bias = (const float*)d_in[2];
    float* out = (float*)d_out;

    int DOUT = in_sizes[2];        // 1024
    int M = in_sizes[0] / DIN;     // 32768

    char* ws  = (char*)d_ws;
    char* wq  = ws;
    float* wsc = (float*)(wq + (size_t)DOUT * DIN);

    quant_w<<<DOUT / 4, 256, 0, stream>>>(w, wq, wsc);
    gemm_i8_fused<<<M / 64, 1024, 0, stream>>>(x, wq, wsc, bias, out, DOUT);
}